// Round 1
// baseline (27.202 us; speedup 1.0000x reference)
//
#include <hip/hip_runtime.h>
#include <math.h>

// PoolingConnection: out[k,i,j] = max(s[k, 6i:6i+64, 6j:6j+64]) clipped at 384.
// F=128, H=W=384, stride=6, window=64 (=H//stride), out = [128,64,64].
// Separable: pool along W first (wave-per-row, shuffle sliding-window max),
// then pool along H (wave per (k,i), coalesced column walk over tmp).

constexpr int F  = 128;
constexpr int H  = 384;
constexpr int W  = 384;
constexpr int ST = 6;
constexpr int OH = 64;   // H / ST
constexpr int OW = 64;   // W / ST

#define NINF (-__builtin_huge_valf())

// shuffle value from lane (lane+d); lanes beyond 63 contribute -inf
// (this also implements the right-edge window clipping).
__device__ __forceinline__ float sh_ninf(float v, int lane, int d) {
    float r = __shfl(v, lane + d, 64);
    return (lane + d > 63) ? NINF : r;
}

// ---------------- Kernel A: max-pool along W ----------------
// One wave per input row. Lane l owns cols [6l, 6l+5].
// Window j = cols 6j..6j+63 = lane j (all 6) + lanes j+1..j+9 (all 6) +
//            lane j+10 (first 4 elements).
__global__ __launch_bounds__(256) void pool_w_kernel(const float* __restrict__ s,
                                                     float* __restrict__ tmp) {
    const int gtid = blockIdx.x * 256 + threadIdx.x;
    const int wid  = gtid >> 6;        // (k*H + r)
    const int lane = gtid & 63;
    if (wid >= F * H) return;

    const float* row = s + (size_t)wid * W + lane * 6;
    const float2 e0 = *reinterpret_cast<const float2*>(row);       // c0,c1
    const float2 e1 = *reinterpret_cast<const float2*>(row + 2);   // c2,c3
    const float2 e2 = *reinterpret_cast<const float2*>(row + 4);   // c4,c5

    const float p3 = fmaxf(fmaxf(e0.x, e0.y), fmaxf(e1.x, e1.y)); // max of first 4
    const float m  = fmaxf(p3, fmaxf(e2.x, e2.y));                // max of all 6

    // sliding max over lanes [l .. l+9] of m  (widths 2 -> 4 -> 8 -> 10)
    const float a1 = fmaxf(m,  sh_ninf(m,  lane, 1));  // [l, l+1]
    const float a2 = fmaxf(a1, sh_ninf(a1, lane, 2));  // [l .. l+3]
    const float a3 = fmaxf(a2, sh_ninf(a2, lane, 4));  // [l .. l+7]
    const float a4 = fmaxf(a3, sh_ninf(a1, lane, 8));  // [l .. l+9]
    const float r  = fmaxf(a4, sh_ninf(p3, lane, 10)); // + first 4 of lane l+10

    tmp[(size_t)wid * OW + lane] = r;                  // coalesced 256B/wave
}

// ---------------- Kernel B: max-pool along H ----------------
// One wave per (k, i). Lane = j. Coalesced walk down 64 rows of tmp.
__global__ __launch_bounds__(256) void pool_h_kernel(const float* __restrict__ tmp,
                                                     float* __restrict__ out) {
    const int gtid = blockIdx.x * 256 + threadIdx.x;
    const int wid  = gtid >> 6;        // k*OH + i
    const int lane = gtid & 63;        // j
    if (wid >= F * OH) return;

    const int k  = wid >> 6;
    const int i  = wid & 63;
    const int r0 = i * ST;
    const int limit = min(64, H - r0); // bottom clipping (i >= 54)

    const float* base = tmp + ((size_t)k * H + r0) * OW + lane;
    float acc = NINF;
    int t = 0;
    for (; t + 4 <= limit; t += 4) {
        const float v0 = base[(size_t)(t + 0) * OW];
        const float v1 = base[(size_t)(t + 1) * OW];
        const float v2 = base[(size_t)(t + 2) * OW];
        const float v3 = base[(size_t)(t + 3) * OW];
        acc = fmaxf(acc, fmaxf(fmaxf(v0, v1), fmaxf(v2, v3)));
    }
    for (; t < limit; ++t) acc = fmaxf(acc, base[(size_t)t * OW]);

    out[(size_t)wid * OW + lane] = acc;                // coalesced 256B/wave
}

// ---------------- Fallback: direct (no workspace needed) ----------------
// Block per (k,i): 384 threads column-reduce 64 rows into LDS, then wave 0
// does the same shuffle sliding-window along W.
__global__ __launch_bounds__(384) void pool_direct_kernel(const float* __restrict__ s,
                                                          float* __restrict__ out) {
    __shared__ float colmax[W];
    const int k  = blockIdx.x >> 6;
    const int i  = blockIdx.x & 63;
    const int c  = threadIdx.x;
    const int r0 = i * ST;
    const int rl = min(64, H - r0);

    const float* base = s + ((size_t)k * H + r0) * W + c;
    float acc = NINF;
    for (int t = 0; t < rl; ++t) acc = fmaxf(acc, base[(size_t)t * W]);
    colmax[c] = acc;
    __syncthreads();

    if (threadIdx.x < 64) {
        const int lane = threadIdx.x;
        const float* p = colmax + lane * 6;
        const float p3 = fmaxf(fmaxf(p[0], p[1]), fmaxf(p[2], p[3]));
        const float m  = fmaxf(p3, fmaxf(p[4], p[5]));
        const float a1 = fmaxf(m,  sh_ninf(m,  lane, 1));
        const float a2 = fmaxf(a1, sh_ninf(a1, lane, 2));
        const float a3 = fmaxf(a2, sh_ninf(a2, lane, 4));
        const float a4 = fmaxf(a3, sh_ninf(a1, lane, 8));
        const float r  = fmaxf(a4, sh_ninf(p3, lane, 10));
        out[((size_t)k * OH + i) * OW + lane] = r;
    }
}

extern "C" void kernel_launch(void* const* d_in, const int* in_sizes, int n_in,
                              void* d_out, int out_size, void* d_ws, size_t ws_size,
                              hipStream_t stream) {
    const float* s  = (const float*)d_in[0];
    float* out      = (float*)d_out;

    const size_t tmp_bytes = (size_t)F * H * OW * sizeof(float); // 12.58 MB

    if (ws_size >= tmp_bytes) {
        float* tmp = (float*)d_ws;
        // Kernel A: F*H waves, 64 lanes each -> 12288 blocks of 256
        const int blocksA = (F * H * 64 + 255) / 256;
        pool_w_kernel<<<blocksA, 256, 0, stream>>>(s, tmp);
        // Kernel B: F*OH waves -> 2048 blocks of 256
        const int blocksB = (F * OH * 64 + 255) / 256;
        pool_h_kernel<<<blocksB, 256, 0, stream>>>(tmp, out);
    } else {
        pool_direct_kernel<<<F * OH, 384, 0, stream>>>(s, out);
    }
}

// Round 2
// 19.767 us; speedup vs baseline: 1.3761x; 1.3761x over previous
//
#include <hip/hip_runtime.h>
#include <math.h>

// PoolingConnection fused: out[k,i,j] = max(s[k, 6i:6i+64, 6j:6j+64]) clipped at 384.
// F=128, H=W=384, stride=6, window=64, out=[128,64,64].
// One block per (k, half): phase 1 pools along W into LDS (wave-per-row shuffle
// sliding max), phase 2 pools along H via 6-row segment maxes (separable again).

constexpr int F  = 128;
constexpr int H  = 384;
constexpr int W  = 384;
constexpr int ST = 6;
constexpr int OH = 64;
constexpr int OW = 64;

#define NINF (-__builtin_huge_valf())

// shuffle value from lane (lane+d); lanes beyond 63 contribute -inf
// (implements the right-edge window clipping for free).
__device__ __forceinline__ float sh_ninf(float v, int lane, int d) {
    float r = __shfl(v, lane + d, 64);
    return (lane + d > 63) ? NINF : r;
}

// Block = (k, half). half 0: output rows 0..31, input rows 0..249 (250 rows).
//                    half 1: output rows 32..63, input rows 192..383 (192 rows).
__global__ __launch_bounds__(1024) void pool_fused_kernel(const float* __restrict__ s,
                                                          float* __restrict__ out) {
    __shared__ float rowmax[250][64];   // 62.5 KiB
    __shared__ float segm[42][64];      // 10.5 KiB  max of rows 6g..6g+5
    __shared__ float segp[42][64];      // 10.5 KiB  max of rows 6g..6g+3

    const int k     = blockIdx.x >> 1;
    const int half  = blockIdx.x & 1;
    const int i0    = half * 32;
    const int rbeg  = i0 * ST;                 // 0 or 192
    const int nrows = half ? (H - 192) : 250;  // 192 or 250

    const int tid  = threadIdx.x;
    const int wv   = tid >> 6;                 // 0..15
    const int lane = tid & 63;

    // ---- Phase 1: pool along W, one wave per input row ----
    // Lane l owns cols [6l, 6l+5]. Window j = lane j (6) + lanes j+1..j+9 (6 each)
    // + first 4 of lane j+10.
    const float* srow_base = s + ((size_t)k * H + rbeg) * W + lane * 6;
    for (int rl = wv; rl < nrows; rl += 16) {
        const float* row = srow_base + (size_t)rl * W;
        const float2 e0 = *reinterpret_cast<const float2*>(row);
        const float2 e1 = *reinterpret_cast<const float2*>(row + 2);
        const float2 e2 = *reinterpret_cast<const float2*>(row + 4);

        const float p3 = fmaxf(fmaxf(e0.x, e0.y), fmaxf(e1.x, e1.y)); // first 4
        const float m  = fmaxf(p3, fmaxf(e2.x, e2.y));                // all 6

        const float a1 = fmaxf(m,  sh_ninf(m,  lane, 1));   // [l, l+1]
        const float a2 = fmaxf(a1, sh_ninf(a1, lane, 2));   // [l .. l+3]
        const float a3 = fmaxf(a2, sh_ninf(a2, lane, 4));   // [l .. l+7]
        const float a4 = fmaxf(a3, sh_ninf(a1, lane, 8));   // [l .. l+9]
        const float r  = fmaxf(a4, sh_ninf(p3, lane, 10));  // + 4 of l+10

        rowmax[rl][lane] = r;
    }
    __syncthreads();

    // ---- Phase 2a: 6-row segment maxes along H ----
    // segm[gl] = max rows 6gl..6gl+5, segp[gl] = max rows 6gl..6gl+3,
    // guard rl >= nrows -> -inf (bottom clipping).
    for (int job = tid; job < 42 * 64; job += 1024) {
        const int gl = job >> 6;
        const int j  = job & 63;
        const int r0 = gl * 6;
        float m6 = NINF, m4 = NINF;
        #pragma unroll
        for (int t = 0; t < 6; ++t) {
            const float v = (r0 + t < nrows) ? rowmax[r0 + t][j] : NINF;
            m6 = fmaxf(m6, v);
            if (t < 4) m4 = fmaxf(m4, v);
        }
        segm[gl][j] = m6;
        segp[gl][j] = m4;
    }
    __syncthreads();

    // ---- Phase 2b: out[i] = max(segm[li..li+9], segp[li+10]) ----
    for (int job = tid; job < 32 * 64; job += 1024) {
        const int li = job >> 6;
        const int j  = job & 63;
        float acc = segp[li + 10][j];
        #pragma unroll
        for (int t = 0; t < 10; ++t) acc = fmaxf(acc, segm[li + t][j]);
        out[((size_t)k * OH + i0 + li) * OW + j] = acc;   // coalesced
    }
}

extern "C" void kernel_launch(void* const* d_in, const int* in_sizes, int n_in,
                              void* d_out, int out_size, void* d_ws, size_t ws_size,
                              hipStream_t stream) {
    const float* s = (const float*)d_in[0];
    float* out     = (float*)d_out;
    pool_fused_kernel<<<F * 2, 1024, 0, stream>>>(s, out);
}